// Round 5
// baseline (1158.581 us; speedup 1.0000x reference)
//
#include <hip/hip_runtime.h>
#include <stdint.h>

#define N_NODES 100000
#define N_EDGES 600000
#define DMODEL  128
#define NLAYERS 4
#define NGRAPH  128
#define NCLASS  10
#define BN_EPS  1e-5f
#define NSLOT   32     // stat partial slots (atomic contention spreading)

typedef __bf16 bf16x8 __attribute__((ext_vector_type(8)));
typedef __bf16 bf16x2 __attribute__((ext_vector_type(2)));
typedef float  f32x4  __attribute__((ext_vector_type(4)));

// ---------------- zero-init scratch we accumulate into ----------------
__global__ void k_zero(int* __restrict__ deg, float* __restrict__ statpart,
                       float* __restrict__ psum) {
  int i = blockIdx.x * 256 + threadIdx.x;
  if (i < N_NODES) deg[i] = 0;
  if (i < NSLOT * 2 * DMODEL) statpart[i] = 0.0f;
  if (i < NGRAPH * DMODEL) psum[i] = 0.0f;
}

// ---------------- embedding gather: h[i,d] = bf16(emb[x[i],d]) ----------------
__global__ void k_embed(const int* __restrict__ x, const float* __restrict__ emb,
                        __bf16* __restrict__ h) {
  int idx = blockIdx.x * 256 + threadIdx.x;        // over N*D/2
  if (idx >= N_NODES * DMODEL / 2) return;
  int i = idx >> 6;
  int p = idx & 63;
  float2 v = *(const float2*)(emb + (size_t)x[i] * DMODEL + p * 2);
  bf16x2 o;
  o[0] = (__bf16)v.x;
  o[1] = (__bf16)v.y;
  *(bf16x2*)(h + (size_t)i * DMODEL + p * 2) = o;
}

// ------- transpose + split-cvt weights: whi+wlo ≈ w^T in 2x bf16 -------
__global__ void k_cvtw(const float* __restrict__ w1, const float* __restrict__ w2,
                       __bf16* __restrict__ wt_hi, __bf16* __restrict__ wt_lo) {
  int idx = blockIdx.x * 256 + threadIdx.x;   // L*2*D*D = 131072
  if (idx >= NLAYERS * 2 * DMODEL * DMODEL) return;
  int mat = idx >> 14;
  int rem = idx & 16383;
  int n = rem >> 7;
  int k = rem & 127;
  int l = mat >> 1;
  int which = mat & 1;
  const float* w = which ? w2 : w1;
  float v = w[(size_t)l * DMODEL * DMODEL + (size_t)k * DMODEL + n];
  __bf16 hi = (__bf16)v;
  wt_hi[idx] = hi;
  wt_lo[idx] = (__bf16)(v - (float)hi);
}

// ---------------- CSR build ----------------
__global__ void k_hist(const int* __restrict__ dst, int* __restrict__ deg) {
  int e = blockIdx.x * 256 + threadIdx.x;
  if (e < N_EDGES) atomicAdd(&deg[dst[e]], 1);
}

__global__ void k_scan1(const int* __restrict__ deg, int* __restrict__ out,
                        int* __restrict__ bsum, int n) {
  __shared__ int lds[256];
  int t = threadIdx.x;
  int idx = blockIdx.x * 256 + t;
  int v = (idx < n) ? deg[idx] : 0;
  int val = v;
  lds[t] = val;
  for (int ofs = 1; ofs < 256; ofs <<= 1) {
    __syncthreads();
    int u = (t >= ofs) ? lds[t - ofs] : 0;
    __syncthreads();
    val += u;
    lds[t] = val;
  }
  if (idx < n) out[idx] = val - v;           // exclusive within chunk
  if (t == 255) bsum[blockIdx.x] = val;      // chunk total
}

__global__ void k_scan2(const int* __restrict__ bsum, int* __restrict__ bsumx, int nb) {
  __shared__ int lds[512];
  int t = threadIdx.x;
  int v = (t < nb) ? bsum[t] : 0;
  int val = v;
  lds[t] = val;
  for (int ofs = 1; ofs < 512; ofs <<= 1) {
    __syncthreads();
    int u = (t >= ofs) ? lds[t - ofs] : 0;
    __syncthreads();
    val += u;
    lds[t] = val;
  }
  if (t < nb) bsumx[t] = val - v;
}

__global__ void k_scan3(int* __restrict__ row_start, int* __restrict__ cursor,
                        const int* __restrict__ bsumx, int n, int total) {
  int idx = blockIdx.x * 256 + threadIdx.x;
  if (idx < n) {
    int v = row_start[idx] + bsumx[blockIdx.x];
    row_start[idx] = v;
    cursor[idx] = v;
  }
  if (idx == 0) row_start[n] = total;
}

__global__ void k_scatter(const int* __restrict__ ei, const float* __restrict__ ea,
                          int* __restrict__ cursor, int* __restrict__ csr_src,
                          float* __restrict__ ca0, float* __restrict__ ca1) {
  int e = blockIdx.x * 256 + threadIdx.x;
  if (e >= N_EDGES) return;
  int s = ei[e];
  int d = ei[N_EDGES + e];
  int pos = atomicAdd(&cursor[d], 1);
  csr_src[pos] = s;
  ca0[pos] = ea[2 * e];
  ca1[pos] = ea[2 * e + 1];
}

// ------- message + aggregate: z = act(h_i) + sum_in relu(act(h_src) + edge_lin) -----
// act(h) = relu(s*h + t) when hasT (deferred BN+relu of previous layer), else identity.
// One wave per node: 64 lanes x 2 channels (bf16x2 loads). 4 nodes per block.
__global__ void __launch_bounds__(256) k_agg(
    const __bf16* __restrict__ h, const int* __restrict__ row_start,
    const int* __restrict__ csr_src, const float* __restrict__ ca0,
    const float* __restrict__ ca1,
    const float* __restrict__ ew,   // edge_w + l*2*D, layout [2][D]
    const float* __restrict__ ebp,  // edge_b + l*D
    const float* __restrict__ sIn, const float* __restrict__ tIn, int hasT,
    __bf16* __restrict__ z) {
  int node = blockIdx.x * 4 + (threadIdx.x >> 6);
  if (node >= N_NODES) return;
  int lane = threadIdx.x & 63;
  int d0 = lane * 2;

  float ew0a = ew[d0],          ew0b = ew[d0 + 1];
  float ew1a = ew[DMODEL + d0], ew1b = ew[DMODEL + d0 + 1];
  float eba = ebp[d0],          ebb = ebp[d0 + 1];
  float sa = 1.0f, ta = 0.0f, sb = 1.0f, tb = 0.0f;
  if (hasT) {
    sa = sIn[d0]; ta = tIn[d0];
    sb = sIn[d0 + 1]; tb = tIn[d0 + 1];
  }

  bf16x2 hv = *(const bf16x2*)(h + (size_t)node * DMODEL + d0);
  float r0 = (float)hv[0];
  float r1 = (float)hv[1];
  float acc0 = hasT ? fmaxf(sa * r0 + ta, 0.0f) : r0;   // self term
  float acc1 = hasT ? fmaxf(sb * r1 + tb, 0.0f) : r1;

  int j0 = row_start[node];
  int j1 = row_start[node + 1];
  for (int j = j0; j < j1; ++j) {
    int src = csr_src[j];
    float a0 = ca0[j];
    float a1 = ca1[j];
    bf16x2 sv = *(const bf16x2*)(h + (size_t)src * DMODEL + d0);
    float f0 = (float)sv[0];
    float f1 = (float)sv[1];
    if (hasT) {
      f0 = fmaxf(sa * f0 + ta, 0.0f);
      f1 = fmaxf(sb * f1 + tb, 0.0f);
    }
    acc0 += fmaxf(f0 + a0 * ew0a + a1 * ew1a + eba, 0.0f);
    acc1 += fmaxf(f1 + a0 * ew0b + a1 * ew1b + ebb, 0.0f);
  }
  bf16x2 o;
  o[0] = (__bf16)acc0;
  o[1] = (__bf16)acc1;
  *(bf16x2*)(z + (size_t)node * DMODEL + d0) = o;
}

// ---------------- GEMM: Y = act(X) @ W + bias  (bf16 MFMA, split-W precision) -------
// act(x) = relu(sIn[k]*x + tIn[k]) when applyIn. X:[N,128] bf16. Whi/Wlo:[n][k] bf16,
// Whi+Wlo ≈ f32 W (weight rounding error eliminated; 2 MFMAs per fragment).
// 256 thr = 4 waves; wave w: rows blk*64+w*16 .. +15, all 128 cols.
// Fragment maps (m89/m92): A[m=lane&15][k=quad*8+j], B[n=lane&15][k=quad*8+j],
// C/D col=lane&15, row=quad*4+reg.
__global__ void __launch_bounds__(256) k_gemm(
    const __bf16* __restrict__ X,
    const __bf16* __restrict__ Whi, const __bf16* __restrict__ Wlo,
    const float* __restrict__ bias,
    const float* __restrict__ sIn, const float* __restrict__ tIn, int applyIn,
    __bf16* __restrict__ Y,
    float* __restrict__ statpart) {
  int wave = threadIdx.x >> 6;
  int lane = threadIdx.x & 63;
  int n16 = lane & 15;
  int quad = lane >> 4;
  int m0 = blockIdx.x * 64 + wave * 16;
  int rowA = m0 + n16;

  f32x4 acc[8];
  for (int ct = 0; ct < 8; ++ct)
    for (int r = 0; r < 4; ++r) acc[ct][r] = 0.0f;

  const __bf16* xrow = X + (size_t)rowA * DMODEL;

#pragma unroll
  for (int kk = 0; kk < 4; ++kk) {
    int k0 = kk * 32 + quad * 8;
    bf16x8 a;
    if (rowA < N_NODES) {
      a = *(const bf16x8*)(xrow + k0);
      if (applyIn) {
#pragma unroll
        for (int j = 0; j < 8; ++j) {
          float f = (float)a[j];
          f = fmaxf(sIn[k0 + j] * f + tIn[k0 + j], 0.0f);
          a[j] = (__bf16)f;
        }
      }
    } else {
#pragma unroll
      for (int j = 0; j < 8; ++j) a[j] = (__bf16)0.0f;
    }
#pragma unroll
    for (int ct = 0; ct < 8; ++ct) {
      size_t woff = (size_t)(ct * 16 + n16) * DMODEL + k0;
      bf16x8 bhi = *(const bf16x8*)(Whi + woff);
      bf16x8 blo = *(const bf16x8*)(Wlo + woff);
      acc[ct] = __builtin_amdgcn_mfma_f32_16x16x32_bf16(a, bhi, acc[ct], 0, 0, 0);
      acc[ct] = __builtin_amdgcn_mfma_f32_16x16x32_bf16(a, blo, acc[ct], 0, 0, 0);
    }
  }

  // epilogue: bias add, bf16 store, column stats in f32 pre-rounding
  int slot = (blockIdx.x * 4 + wave) & (NSLOT - 1);
#pragma unroll
  for (int ct = 0; ct < 8; ++ct) {
    int c = ct * 16 + n16;
    float bc = bias[c];
    float sum = 0.0f;
    float sq = 0.0f;
#pragma unroll
    for (int r = 0; r < 4; ++r) {
      int row = m0 + quad * 4 + r;
      if (row < N_NODES) {
        float v = acc[ct][r] + bc;
        Y[(size_t)row * DMODEL + c] = (__bf16)v;
        sum += v;
        sq += v * v;
      }
    }
    sum += __shfl_xor(sum, 16);
    sq  += __shfl_xor(sq, 16);
    sum += __shfl_xor(sum, 32);
    sq  += __shfl_xor(sq, 32);
    if (quad == 0) {
      atomicAdd(&statpart[slot * (2 * DMODEL) + c], sum);
      atomicAdd(&statpart[slot * (2 * DMODEL) + DMODEL + c], sq);
    }
  }
}

// ------- fold stat partials into BN scale/shift, and re-zero partials -------
__global__ void k_bnfin(float* __restrict__ statpart,
                        const float* __restrict__ gamma, const float* __restrict__ beta,
                        float* __restrict__ sOut, float* __restrict__ tOut) {
  int d = threadIdx.x;   // 128
  float sum = 0.0f;
  float sq = 0.0f;
  for (int p = 0; p < NSLOT; ++p) {
    sum += statpart[p * (2 * DMODEL) + d];
    sq  += statpart[p * (2 * DMODEL) + DMODEL + d];
  }
  float mean = sum * (1.0f / N_NODES);
  float var = sq * (1.0f / N_NODES) - mean * mean;
  float inv = rsqrtf(var + BN_EPS);
  float s = gamma[d] * inv;
  sOut[d] = s;
  tOut[d] = beta[d] - mean * s;
  for (int p = 0; p < NSLOT; ++p) {
    statpart[p * (2 * DMODEL) + d] = 0.0f;
    statpart[p * (2 * DMODEL) + DMODEL + d] = 0.0f;
  }
}

// ------- graph boundaries by binary search over sorted batch -------
__global__ void k_gstart(const int* __restrict__ batch, int* __restrict__ gstart) {
  int g = blockIdx.x * 256 + threadIdx.x;
  if (g > NGRAPH) return;
  int lo = 0;
  int hi = N_NODES;
  while (lo < hi) {
    int mid = (lo + hi) >> 1;
    if (batch[mid] < g) lo = mid + 1; else hi = mid;
  }
  gstart[g] = lo;   // first node with batch >= g; gstart[G] = N
}

// ------- pooling partial sums of raw h (affine deferred to classifier) -------
__global__ void k_pool(const __bf16* __restrict__ h, const int* __restrict__ gstart,
                       float* __restrict__ psum) {
  int g = blockIdx.x;
  int slice = blockIdx.y;   // 0..7
  int lane = threadIdx.x;   // 64
  int d0 = lane * 2;
  int i0 = gstart[g];
  int i1 = gstart[g + 1];
  float a0 = 0.0f;
  float a1 = 0.0f;
  for (int i = i0 + slice; i < i1; i += 8) {
    bf16x2 v = *(const bf16x2*)(h + (size_t)i * DMODEL + d0);
    a0 += (float)v[0];
    a1 += (float)v[1];
  }
  atomicAdd(&psum[g * DMODEL + d0], a0);
  atomicAdd(&psum[g * DMODEL + d0 + 1], a1);
}

// ------- classifier: applies final BN affine + mean, then Linear-ReLU-Linear -------
__global__ void k_classifier(const float* __restrict__ psum, const int* __restrict__ gstart,
                             const float* __restrict__ s2, const float* __restrict__ t2,
                             const float* __restrict__ cw1, const float* __restrict__ cb1,
                             const float* __restrict__ cw2, const float* __restrict__ cb2,
                             float* __restrict__ out) {
  __shared__ float pl[DMODEL];
  __shared__ float hid[DMODEL];
  int g = blockIdx.x;
  int d = threadIdx.x;
  int cnt = gstart[g + 1] - gstart[g];
  pl[d] = (cnt > 0) ? (s2[d] * (psum[g * DMODEL + d] / (float)cnt) + t2[d]) : 0.0f;
  __syncthreads();
  float acc = cb1[d];
  for (int k = 0; k < DMODEL; ++k) acc += pl[k] * cw1[k * DMODEL + d];
  hid[d] = fmaxf(acc, 0.0f);
  __syncthreads();
  if (d < NCLASS) {
    float acc2 = cb2[d];
    for (int k = 0; k < DMODEL; ++k) acc2 += hid[k] * cw2[k * NCLASS + d];
    out[g * NCLASS + d] = acc2;
  }
}

// ---------------- launcher ----------------
extern "C" void kernel_launch(void* const* d_in, const int* in_sizes, int n_in,
                              void* d_out, int out_size, void* d_ws, size_t ws_size,
                              hipStream_t stream) {
  const int*   x      = (const int*)d_in[0];
  const int*   ei     = (const int*)d_in[1];
  const float* ea     = (const float*)d_in[2];
  const int*   batch  = (const int*)d_in[3];
  const float* emb    = (const float*)d_in[4];
  const float* edge_w = (const float*)d_in[5];
  const float* edge_b = (const float*)d_in[6];
  const float* w1     = (const float*)d_in[7];
  const float* b1     = (const float*)d_in[8];
  const float* g1     = (const float*)d_in[9];
  const float* beta1  = (const float*)d_in[10];
  const float* w2     = (const float*)d_in[11];
  const float* b2     = (const float*)d_in[12];
  const float* ng     = (const float*)d_in[13];
  const float* nb     = (const float*)d_in[14];
  const float* cw1    = (const float*)d_in[15];
  const float* cb1    = (const float*)d_in[16];
  const float* cw2    = (const float*)d_in[17];
  const float* cb2    = (const float*)d_in[18];

  char* ws = (char*)d_ws;
  size_t off = 0;
  auto alloc = [&](size_t bytes) -> void* {
    void* p = ws + off;
    off += (bytes + 255) & ~(size_t)255;
    return p;
  };

  __bf16* h_bf      = (__bf16*)alloc((size_t)N_NODES * DMODEL * sizeof(__bf16));
  __bf16* z_bf      = (__bf16*)alloc((size_t)N_NODES * DMODEL * sizeof(__bf16));
  __bf16* y1_bf     = (__bf16*)alloc((size_t)N_NODES * DMODEL * sizeof(__bf16));
  int*    row_start = (int*)alloc((N_NODES + 1) * sizeof(int));
  int*    cursor    = (int*)alloc(N_NODES * sizeof(int));
  int*    deg       = (int*)alloc(N_NODES * sizeof(int));
  int*    csr_src   = (int*)alloc(N_EDGES * sizeof(int));
  float*  ca0       = (float*)alloc(N_EDGES * sizeof(float));
  float*  ca1       = (float*)alloc(N_EDGES * sizeof(float));
  __bf16* wt_hi     = (__bf16*)alloc((size_t)NLAYERS * 2 * DMODEL * DMODEL * sizeof(__bf16));
  __bf16* wt_lo     = (__bf16*)alloc((size_t)NLAYERS * 2 * DMODEL * DMODEL * sizeof(__bf16));
  float*  statpart  = (float*)alloc((size_t)NSLOT * 2 * DMODEL * sizeof(float));
  float*  st        = (float*)alloc((size_t)NLAYERS * 2 * 2 * DMODEL * sizeof(float));
  int*    gstart    = (int*)alloc((NGRAPH + 1) * sizeof(int));
  float*  psum      = (float*)alloc((size_t)NGRAPH * DMODEL * sizeof(float));
  int*    bsum      = (int*)alloc(512 * sizeof(int));
  int*    bsumx     = (int*)alloc(512 * sizeof(int));

  auto sArr = [&](int l, int which) { return st + ((l * 2 + which) * 2 + 0) * DMODEL; };
  auto tArr = [&](int l, int which) { return st + ((l * 2 + which) * 2 + 1) * DMODEL; };

  const int nbScan = (N_NODES + 255) / 256;              // 391
  const int nbEdge = (N_EDGES + 255) / 256;              // 2344
  const int nbEmb  = (N_NODES * DMODEL / 2 + 255) / 256; // 25000
  const int nbGemm = (N_NODES + 63) / 64;                // 1563
  const int nbAgg  = (N_NODES + 3) / 4;                  // 25000

  k_zero<<<nbScan, 256, 0, stream>>>(deg, statpart, psum);
  k_embed<<<nbEmb, 256, 0, stream>>>(x, emb, h_bf);
  k_cvtw<<<(NLAYERS * 2 * DMODEL * DMODEL) / 256, 256, 0, stream>>>(w1, w2, wt_hi, wt_lo);
  k_hist<<<nbEdge, 256, 0, stream>>>(ei + N_EDGES, deg);
  k_scan1<<<nbScan, 256, 0, stream>>>(deg, row_start, bsum, N_NODES);
  k_scan2<<<1, 512, 0, stream>>>(bsum, bsumx, nbScan);
  k_scan3<<<nbScan, 256, 0, stream>>>(row_start, cursor, bsumx, N_NODES, N_EDGES);
  k_scatter<<<nbEdge, 256, 0, stream>>>(ei, ea, cursor, csr_src, ca0, ca1);
  k_gstart<<<1, 256, 0, stream>>>(batch, gstart);

  for (int l = 0; l < NLAYERS; ++l) {
    const float* sI = (l > 0) ? sArr(l - 1, 1) : (const float*)nullptr;
    const float* tI = (l > 0) ? tArr(l - 1, 1) : (const float*)nullptr;
    k_agg<<<nbAgg, 256, 0, stream>>>(h_bf, row_start, csr_src, ca0, ca1,
                                     edge_w + (size_t)l * 2 * DMODEL,
                                     edge_b + (size_t)l * DMODEL,
                                     sI, tI, (l > 0) ? 1 : 0, z_bf);
    // y1 = z @ w1[l] + b1[l]   (stats -> BN1)
    k_gemm<<<nbGemm, 256, 0, stream>>>(
        z_bf,
        wt_hi + (size_t)(l * 2 + 0) * DMODEL * DMODEL,
        wt_lo + (size_t)(l * 2 + 0) * DMODEL * DMODEL,
        b1 + (size_t)l * DMODEL,
        (const float*)nullptr, (const float*)nullptr, 0,
        y1_bf, statpart);
    k_bnfin<<<1, DMODEL, 0, stream>>>(statpart,
                                      g1 + (size_t)l * DMODEL, beta1 + (size_t)l * DMODEL,
                                      sArr(l, 0), tArr(l, 0));
    // h = relu(BN1(y1)) @ w2[l] + b2[l]   (stats -> BN2, applied by next consumer)
    k_gemm<<<nbGemm, 256, 0, stream>>>(
        y1_bf,
        wt_hi + (size_t)(l * 2 + 1) * DMODEL * DMODEL,
        wt_lo + (size_t)(l * 2 + 1) * DMODEL * DMODEL,
        b2 + (size_t)l * DMODEL,
        sArr(l, 0), tArr(l, 0), 1,
        h_bf, statpart);
    k_bnfin<<<1, DMODEL, 0, stream>>>(statpart,
                                      ng + (size_t)l * DMODEL, nb + (size_t)l * DMODEL,
                                      sArr(l, 1), tArr(l, 1));
  }

  dim3 poolGrid(NGRAPH, 8);
  k_pool<<<poolGrid, 64, 0, stream>>>(h_bf, gstart, psum);
  k_classifier<<<NGRAPH, DMODEL, 0, stream>>>(psum, gstart, sArr(NLAYERS - 1, 1),
                                              tArr(NLAYERS - 1, 1),
                                              cw1, cb1, cw2, cb2, (float*)d_out);
}

// Round 6
// 881.605 us; speedup vs baseline: 1.3142x; 1.3142x over previous
//
#include <hip/hip_runtime.h>
#include <stdint.h>

#define N_NODES 100000
#define N_EDGES 600000
#define DMODEL  128
#define NLAYERS 4
#define NGRAPH  128
#define NCLASS  10
#define BN_EPS  1e-5f
#define NSLOT   32     // stat partial slots (atomic contention spreading)

typedef __bf16 bf16x8 __attribute__((ext_vector_type(8)));
typedef __bf16 bf16x2 __attribute__((ext_vector_type(2)));
typedef float  f32x4  __attribute__((ext_vector_type(4)));

// ---------------- zero-init scratch we accumulate into ----------------
__global__ void k_zero(int* __restrict__ deg, float* __restrict__ statpart,
                       float* __restrict__ psum) {
  int i = blockIdx.x * 256 + threadIdx.x;
  if (i < N_NODES) deg[i] = 0;
  if (i < NSLOT * 2 * DMODEL) statpart[i] = 0.0f;
  if (i < NGRAPH * DMODEL) psum[i] = 0.0f;
}

// ---------------- embedding gather: h[i,d] = bf16(emb[x[i],d]) ----------------
__global__ void k_embed(const int* __restrict__ x, const float* __restrict__ emb,
                        __bf16* __restrict__ h) {
  int idx = blockIdx.x * 256 + threadIdx.x;        // over N*D/2
  if (idx >= N_NODES * DMODEL / 2) return;
  int i = idx >> 6;
  int p = idx & 63;
  float2 v = *(const float2*)(emb + (size_t)x[i] * DMODEL + p * 2);
  bf16x2 o;
  o[0] = (__bf16)v.x;
  o[1] = (__bf16)v.y;
  *(bf16x2*)(h + (size_t)i * DMODEL + p * 2) = o;
}

// ------- transpose + split-cvt weights: whi+wlo ≈ w^T in 2x bf16 -------
__global__ void k_cvtw(const float* __restrict__ w1, const float* __restrict__ w2,
                       __bf16* __restrict__ wt_hi, __bf16* __restrict__ wt_lo) {
  int idx = blockIdx.x * 256 + threadIdx.x;   // L*2*D*D = 131072
  if (idx >= NLAYERS * 2 * DMODEL * DMODEL) return;
  int mat = idx >> 14;
  int rem = idx & 16383;
  int n = rem >> 7;
  int k = rem & 127;
  int l = mat >> 1;
  int which = mat & 1;
  const float* w = which ? w2 : w1;
  float v = w[(size_t)l * DMODEL * DMODEL + (size_t)k * DMODEL + n];
  __bf16 hi = (__bf16)v;
  wt_hi[idx] = hi;
  wt_lo[idx] = (__bf16)(v - (float)hi);
}

// ---------------- CSR build ----------------
__global__ void k_hist(const int* __restrict__ dst, int* __restrict__ deg) {
  int e = blockIdx.x * 256 + threadIdx.x;
  if (e < N_EDGES) atomicAdd(&deg[dst[e]], 1);
}

__global__ void k_scan1(const int* __restrict__ deg, int* __restrict__ out,
                        int* __restrict__ bsum, int n) {
  __shared__ int lds[256];
  int t = threadIdx.x;
  int idx = blockIdx.x * 256 + t;
  int v = (idx < n) ? deg[idx] : 0;
  int val = v;
  lds[t] = val;
  for (int ofs = 1; ofs < 256; ofs <<= 1) {
    __syncthreads();
    int u = (t >= ofs) ? lds[t - ofs] : 0;
    __syncthreads();
    val += u;
    lds[t] = val;
  }
  if (idx < n) out[idx] = val - v;           // exclusive within chunk
  if (t == 255) bsum[blockIdx.x] = val;      // chunk total
}

__global__ void k_scan2(const int* __restrict__ bsum, int* __restrict__ bsumx, int nb) {
  __shared__ int lds[512];
  int t = threadIdx.x;
  int v = (t < nb) ? bsum[t] : 0;
  int val = v;
  lds[t] = val;
  for (int ofs = 1; ofs < 512; ofs <<= 1) {
    __syncthreads();
    int u = (t >= ofs) ? lds[t - ofs] : 0;
    __syncthreads();
    val += u;
    lds[t] = val;
  }
  if (t < nb) bsumx[t] = val - v;
}

__global__ void k_scan3(int* __restrict__ row_start, int* __restrict__ cursor,
                        const int* __restrict__ bsumx, int n, int total) {
  int idx = blockIdx.x * 256 + threadIdx.x;
  if (idx < n) {
    int v = row_start[idx] + bsumx[blockIdx.x];
    row_start[idx] = v;
    cursor[idx] = v;
  }
  if (idx == 0) row_start[n] = total;
}

// pack each edge as 16B {src, a0, a1, pad} at its CSR slot
__global__ void k_scatter(const int* __restrict__ ei, const float* __restrict__ ea,
                          int* __restrict__ cursor, int4* __restrict__ epack) {
  int e = blockIdx.x * 256 + threadIdx.x;
  if (e >= N_EDGES) return;
  int s = ei[e];
  int d = ei[N_EDGES + e];
  int pos = atomicAdd(&cursor[d], 1);
  int4 pk;
  pk.x = s;
  pk.y = __float_as_int(ea[2 * e]);
  pk.z = __float_as_int(ea[2 * e + 1]);
  pk.w = 0;
  epack[pos] = pk;
}

// ------- message + aggregate: z = act(h_i) + sum_in relu(act(h_src) + edge_lin) -----
// act(h) = relu(s*h + t) when hasT (deferred BN+relu of previous layer), else identity.
// One wave per node: 64 lanes x 2 channels. 4 nodes/block. j-loop unrolled 4x with
// independent gathers (MLP); accumulation order kept sequential (identical rounding).
__global__ void __launch_bounds__(256) k_agg(
    const __bf16* __restrict__ h, const int* __restrict__ row_start,
    const int4* __restrict__ epack,
    const float* __restrict__ ew,   // edge_w + l*2*D, layout [2][D]
    const float* __restrict__ ebp,  // edge_b + l*D
    const float* __restrict__ sIn, const float* __restrict__ tIn, int hasT,
    __bf16* __restrict__ z) {
  int node = blockIdx.x * 4 + (threadIdx.x >> 6);
  if (node >= N_NODES) return;
  int lane = threadIdx.x & 63;
  int d0 = lane * 2;

  float ew0a = ew[d0],          ew0b = ew[d0 + 1];
  float ew1a = ew[DMODEL + d0], ew1b = ew[DMODEL + d0 + 1];
  float eba = ebp[d0],          ebb = ebp[d0 + 1];
  float sa = 1.0f, ta = 0.0f, sb = 1.0f, tb = 0.0f;
  if (hasT) {
    sa = sIn[d0]; ta = tIn[d0];
    sb = sIn[d0 + 1]; tb = tIn[d0 + 1];
  }

  bf16x2 hv = *(const bf16x2*)(h + (size_t)node * DMODEL + d0);
  float r0 = (float)hv[0];
  float r1 = (float)hv[1];
  float acc0 = hasT ? fmaxf(sa * r0 + ta, 0.0f) : r0;   // self term
  float acc1 = hasT ? fmaxf(sb * r1 + tb, 0.0f) : r1;

  int j0 = row_start[node];
  int j1 = row_start[node + 1];
  int j = j0;

#define AGG_ONE(E, V)                                                          \
  {                                                                            \
    float a0 = __int_as_float((E).y);                                          \
    float a1 = __int_as_float((E).z);                                          \
    float f0 = (float)(V)[0];                                                  \
    float f1 = (float)(V)[1];                                                  \
    if (hasT) {                                                                \
      f0 = fmaxf(sa * f0 + ta, 0.0f);                                          \
      f1 = fmaxf(sb * f1 + tb, 0.0f);                                          \
    }                                                                          \
    acc0 += fmaxf(f0 + a0 * ew0a + a1 * ew1a + eba, 0.0f);                     \
    acc1 += fmaxf(f1 + a0 * ew0b + a1 * ew1b + ebb, 0.0f);                     \
  }

  for (; j + 4 <= j1; j += 4) {
    int4 e0 = epack[j];
    int4 e1 = epack[j + 1];
    int4 e2 = epack[j + 2];
    int4 e3 = epack[j + 3];
    bf16x2 v0 = *(const bf16x2*)(h + (size_t)e0.x * DMODEL + d0);
    bf16x2 v1 = *(const bf16x2*)(h + (size_t)e1.x * DMODEL + d0);
    bf16x2 v2 = *(const bf16x2*)(h + (size_t)e2.x * DMODEL + d0);
    bf16x2 v3 = *(const bf16x2*)(h + (size_t)e3.x * DMODEL + d0);
    AGG_ONE(e0, v0)
    AGG_ONE(e1, v1)
    AGG_ONE(e2, v2)
    AGG_ONE(e3, v3)
  }
  for (; j < j1; ++j) {
    int4 e0 = epack[j];
    bf16x2 v0 = *(const bf16x2*)(h + (size_t)e0.x * DMODEL + d0);
    AGG_ONE(e0, v0)
  }
#undef AGG_ONE

  bf16x2 o;
  o[0] = (__bf16)acc0;
  o[1] = (__bf16)acc1;
  *(bf16x2*)(z + (size_t)node * DMODEL + d0) = o;
}

// ---------------- GEMM: Y = act(X) @ W + bias  (bf16 MFMA, split-W, LDS-staged) -----
// act(x) = relu(sIn[k]*x + tIn[k]) when applyIn. X:[N,128] bf16. Whi/Wlo:[n][k] bf16,
// Whi+Wlo ≈ f32 W. Block: 256 thr = 4 waves, 256 rows; wave w: rows blk*256+w*64
// (4 m-tiles of 16), all 128 cols. W staged in 64KB LDS with XOR chunk swizzle:
// row n chunk c (8 bf16) stored at chunk c^(n&15) -> quad reads are 2-way/free.
// Fragment maps (m89/m92): A[m=lane&15][k=quad*8+j], B[n=lane&15][k=quad*8+j],
// C/D col=lane&15, row=quad*4+reg.
__global__ void __launch_bounds__(256) k_gemm(
    const __bf16* __restrict__ X,
    const __bf16* __restrict__ Whi, const __bf16* __restrict__ Wlo,
    const float* __restrict__ bias,
    const float* __restrict__ sIn, const float* __restrict__ tIn, int applyIn,
    __bf16* __restrict__ Y,
    float* __restrict__ statpart) {
  __shared__ __align__(16) __bf16 lhi[DMODEL * DMODEL];   // 32 KB
  __shared__ __align__(16) __bf16 llo[DMODEL * DMODEL];   // 32 KB
  int tid = threadIdx.x;

  // stage W: 2048 16B-chunks per matrix, 8 per thread, swizzled placement
#pragma unroll
  for (int i = 0; i < 8; ++i) {
    int lin = i * 256 + tid;      // 0..2047
    int n = lin >> 4;
    int c = lin & 15;
    int sw = c ^ (n & 15);
    bf16x8 vhi = *(const bf16x8*)(Whi + n * DMODEL + c * 8);
    bf16x8 vlo = *(const bf16x8*)(Wlo + n * DMODEL + c * 8);
    *(bf16x8*)(lhi + n * DMODEL + sw * 8) = vhi;
    *(bf16x8*)(llo + n * DMODEL + sw * 8) = vlo;
  }
  __syncthreads();

  int wave = tid >> 6;
  int lane = tid & 63;
  int n16 = lane & 15;
  int quad = lane >> 4;
  int m0 = blockIdx.x * 256 + wave * 64;

  f32x4 acc[4][8];
  for (int t = 0; t < 4; ++t)
    for (int ct = 0; ct < 8; ++ct)
      for (int r = 0; r < 4; ++r) acc[t][ct][r] = 0.0f;

#pragma unroll
  for (int kk = 0; kk < 4; ++kk) {
    int k0 = kk * 32 + quad * 8;
    float sv[8], tv[8];
    if (applyIn) {
      float4 s0 = *(const float4*)(sIn + k0);
      float4 s1 = *(const float4*)(sIn + k0 + 4);
      float4 t0 = *(const float4*)(tIn + k0);
      float4 t1 = *(const float4*)(tIn + k0 + 4);
      sv[0] = s0.x; sv[1] = s0.y; sv[2] = s0.z; sv[3] = s0.w;
      sv[4] = s1.x; sv[5] = s1.y; sv[6] = s1.z; sv[7] = s1.w;
      tv[0] = t0.x; tv[1] = t0.y; tv[2] = t0.z; tv[3] = t0.w;
      tv[4] = t1.x; tv[5] = t1.y; tv[6] = t1.z; tv[7] = t1.w;
    }
    bf16x8 a[4];
#pragma unroll
    for (int t = 0; t < 4; ++t) {
      int row = m0 + t * 16 + n16;
      if (row < N_NODES) {
        a[t] = *(const bf16x8*)(X + (size_t)row * DMODEL + k0);
        if (applyIn) {
#pragma unroll
          for (int jj = 0; jj < 8; ++jj) {
            float f = (float)a[t][jj];
            f = fmaxf(sv[jj] * f + tv[jj], 0.0f);
            a[t][jj] = (__bf16)f;
          }
        }
      } else {
#pragma unroll
        for (int jj = 0; jj < 8; ++jj) a[t][jj] = (__bf16)0.0f;
      }
    }
    int chunk = kk * 4 + quad;
#pragma unroll
    for (int ct = 0; ct < 8; ++ct) {
      int n = ct * 16 + n16;
      int off = n * DMODEL + ((chunk ^ n16) * 8);
      bf16x8 bhi = *(const bf16x8*)(lhi + off);
      bf16x8 blo = *(const bf16x8*)(llo + off);
#pragma unroll
      for (int t = 0; t < 4; ++t) {
        acc[t][ct] = __builtin_amdgcn_mfma_f32_16x16x32_bf16(a[t], bhi, acc[t][ct], 0, 0, 0);
        acc[t][ct] = __builtin_amdgcn_mfma_f32_16x16x32_bf16(a[t], blo, acc[t][ct], 0, 0, 0);
      }
    }
  }

  // epilogue: bias add, bf16 store, column stats (f32, pre-rounding)
  int slot = (blockIdx.x * 4 + wave) & (NSLOT - 1);
#pragma unroll
  for (int ct = 0; ct < 8; ++ct) {
    int c = ct * 16 + n16;
    float bc = bias[c];
    float sum = 0.0f;
    float sq = 0.0f;
#pragma unroll
    for (int t = 0; t < 4; ++t) {
#pragma unroll
      for (int r = 0; r < 4; ++r) {
        int row = m0 + t * 16 + quad * 4 + r;
        if (row < N_NODES) {
          float v = acc[t][ct][r] + bc;
          Y[(size_t)row * DMODEL + c] = (__bf16)v;
          sum += v;
          sq += v * v;
        }
      }
    }
    sum += __shfl_xor(sum, 16);
    sq  += __shfl_xor(sq, 16);
    sum += __shfl_xor(sum, 32);
    sq  += __shfl_xor(sq, 32);
    if (quad == 0) {
      atomicAdd(&statpart[slot * (2 * DMODEL) + c], sum);
      atomicAdd(&statpart[slot * (2 * DMODEL) + DMODEL + c], sq);
    }
  }
}

// ------- fold stat partials into BN scale/shift, and re-zero partials -------
__global__ void k_bnfin(float* __restrict__ statpart,
                        const float* __restrict__ gamma, const float* __restrict__ beta,
                        float* __restrict__ sOut, float* __restrict__ tOut) {
  int d = threadIdx.x;   // 128
  float sum = 0.0f;
  float sq = 0.0f;
  for (int p = 0; p < NSLOT; ++p) {
    sum += statpart[p * (2 * DMODEL) + d];
    sq  += statpart[p * (2 * DMODEL) + DMODEL + d];
  }
  float mean = sum * (1.0f / N_NODES);
  float var = sq * (1.0f / N_NODES) - mean * mean;
  float inv = rsqrtf(var + BN_EPS);
  float s = gamma[d] * inv;
  sOut[d] = s;
  tOut[d] = beta[d] - mean * s;
  for (int p = 0; p < NSLOT; ++p) {
    statpart[p * (2 * DMODEL) + d] = 0.0f;
    statpart[p * (2 * DMODEL) + DMODEL + d] = 0.0f;
  }
}

// ------- graph boundaries by binary search over sorted batch -------
__global__ void k_gstart(const int* __restrict__ batch, int* __restrict__ gstart) {
  int g = blockIdx.x * 256 + threadIdx.x;
  if (g > NGRAPH) return;
  int lo = 0;
  int hi = N_NODES;
  while (lo < hi) {
    int mid = (lo + hi) >> 1;
    if (batch[mid] < g) lo = mid + 1; else hi = mid;
  }
  gstart[g] = lo;   // first node with batch >= g; gstart[G] = N
}

// ------- pooling partial sums of raw h (affine deferred to classifier) -------
__global__ void k_pool(const __bf16* __restrict__ h, const int* __restrict__ gstart,
                       float* __restrict__ psum) {
  int g = blockIdx.x;
  int slice = blockIdx.y;   // 0..7
  int lane = threadIdx.x;   // 64
  int d0 = lane * 2;
  int i0 = gstart[g];
  int i1 = gstart[g + 1];
  float a0 = 0.0f;
  float a1 = 0.0f;
  for (int i = i0 + slice; i < i1; i += 8) {
    bf16x2 v = *(const bf16x2*)(h + (size_t)i * DMODEL + d0);
    a0 += (float)v[0];
    a1 += (float)v[1];
  }
  atomicAdd(&psum[g * DMODEL + d0], a0);
  atomicAdd(&psum[g * DMODEL + d0 + 1], a1);
}

// ------- classifier: applies final BN affine + mean, then Linear-ReLU-Linear -------
__global__ void k_classifier(const float* __restrict__ psum, const int* __restrict__ gstart,
                             const float* __restrict__ s2, const float* __restrict__ t2,
                             const float* __restrict__ cw1, const float* __restrict__ cb1,
                             const float* __restrict__ cw2, const float* __restrict__ cb2,
                             float* __restrict__ out) {
  __shared__ float pl[DMODEL];
  __shared__ float hid[DMODEL];
  int g = blockIdx.x;
  int d = threadIdx.x;
  int cnt = gstart[g + 1] - gstart[g];
  pl[d] = (cnt > 0) ? (s2[d] * (psum[g * DMODEL + d] / (float)cnt) + t2[d]) : 0.0f;
  __syncthreads();
  float acc = cb1[d];
  for (int k = 0; k < DMODEL; ++k) acc += pl[k] * cw1[k * DMODEL + d];
  hid[d] = fmaxf(acc, 0.0f);
  __syncthreads();
  if (d < NCLASS) {
    float acc2 = cb2[d];
    for (int k = 0; k < DMODEL; ++k) acc2 += hid[k] * cw2[k * NCLASS + d];
    out[g * NCLASS + d] = acc2;
  }
}

// ---------------- launcher ----------------
extern "C" void kernel_launch(void* const* d_in, const int* in_sizes, int n_in,
                              void* d_out, int out_size, void* d_ws, size_t ws_size,
                              hipStream_t stream) {
  const int*   x      = (const int*)d_in[0];
  const int*   ei     = (const int*)d_in[1];
  const float* ea     = (const float*)d_in[2];
  const int*   batch  = (const int*)d_in[3];
  const float* emb    = (const float*)d_in[4];
  const float* edge_w = (const float*)d_in[5];
  const float* edge_b = (const float*)d_in[6];
  const float* w1     = (const float*)d_in[7];
  const float* b1     = (const float*)d_in[8];
  const float* g1     = (const float*)d_in[9];
  const float* beta1  = (const float*)d_in[10];
  const float* w2     = (const float*)d_in[11];
  const float* b2     = (const float*)d_in[12];
  const float* ng     = (const float*)d_in[13];
  const float* nb     = (const float*)d_in[14];
  const float* cw1    = (const float*)d_in[15];
  const float* cb1    = (const float*)d_in[16];
  const float* cw2    = (const float*)d_in[17];
  const float* cb2    = (const float*)d_in[18];

  char* ws = (char*)d_ws;
  size_t off = 0;
  auto alloc = [&](size_t bytes) -> void* {
    void* p = ws + off;
    off += (bytes + 255) & ~(size_t)255;
    return p;
  };

  __bf16* h_bf      = (__bf16*)alloc((size_t)N_NODES * DMODEL * sizeof(__bf16));
  __bf16* z_bf      = (__bf16*)alloc((size_t)N_NODES * DMODEL * sizeof(__bf16));
  __bf16* y1_bf     = (__bf16*)alloc((size_t)N_NODES * DMODEL * sizeof(__bf16));
  int*    row_start = (int*)alloc((N_NODES + 1) * sizeof(int));
  int*    cursor    = (int*)alloc(N_NODES * sizeof(int));
  int*    deg       = (int*)alloc(N_NODES * sizeof(int));
  int4*   epack     = (int4*)alloc((size_t)N_EDGES * sizeof(int4));
  __bf16* wt_hi     = (__bf16*)alloc((size_t)NLAYERS * 2 * DMODEL * DMODEL * sizeof(__bf16));
  __bf16* wt_lo     = (__bf16*)alloc((size_t)NLAYERS * 2 * DMODEL * DMODEL * sizeof(__bf16));
  float*  statpart  = (float*)alloc((size_t)NSLOT * 2 * DMODEL * sizeof(float));
  float*  st        = (float*)alloc((size_t)NLAYERS * 2 * 2 * DMODEL * sizeof(float));
  int*    gstart    = (int*)alloc((NGRAPH + 1) * sizeof(int));
  float*  psum      = (float*)alloc((size_t)NGRAPH * DMODEL * sizeof(float));
  int*    bsum      = (int*)alloc(512 * sizeof(int));
  int*    bsumx     = (int*)alloc(512 * sizeof(int));

  auto sArr = [&](int l, int which) { return st + ((l * 2 + which) * 2 + 0) * DMODEL; };
  auto tArr = [&](int l, int which) { return st + ((l * 2 + which) * 2 + 1) * DMODEL; };

  const int nbScan = (N_NODES + 255) / 256;              // 391
  const int nbEdge = (N_EDGES + 255) / 256;              // 2344
  const int nbEmb  = (N_NODES * DMODEL / 2 + 255) / 256; // 25000
  const int nbGemm = (N_NODES + 255) / 256;              // 391 (256 rows/block)
  const int nbAgg  = (N_NODES + 3) / 4;                  // 25000

  k_zero<<<nbScan, 256, 0, stream>>>(deg, statpart, psum);
  k_embed<<<nbEmb, 256, 0, stream>>>(x, emb, h_bf);
  k_cvtw<<<(NLAYERS * 2 * DMODEL * DMODEL) / 256, 256, 0, stream>>>(w1, w2, wt_hi, wt_lo);
  k_hist<<<nbEdge, 256, 0, stream>>>(ei + N_EDGES, deg);
  k_scan1<<<nbScan, 256, 0, stream>>>(deg, row_start, bsum, N_NODES);
  k_scan2<<<1, 512, 0, stream>>>(bsum, bsumx, nbScan);
  k_scan3<<<nbScan, 256, 0, stream>>>(row_start, cursor, bsumx, N_NODES, N_EDGES);
  k_scatter<<<nbEdge, 256, 0, stream>>>(ei, ea, cursor, epack);
  k_gstart<<<1, 256, 0, stream>>>(batch, gstart);

  for (int l = 0; l < NLAYERS; ++l) {
    const float* sI = (l > 0) ? sArr(l - 1, 1) : (const float*)nullptr;
    const float* tI = (l > 0) ? tArr(l - 1, 1) : (const float*)nullptr;
    k_agg<<<nbAgg, 256, 0, stream>>>(h_bf, row_start, epack,
                                     edge_w + (size_t)l * 2 * DMODEL,
                                     edge_b + (size_t)l * DMODEL,
                                     sI, tI, (l > 0) ? 1 : 0, z_bf);
    // y1 = z @ w1[l] + b1[l]   (stats -> BN1)
    k_gemm<<<nbGemm, 256, 0, stream>>>(
        z_bf,
        wt_hi + (size_t)(l * 2 + 0) * DMODEL * DMODEL,
        wt_lo + (size_t)(l * 2 + 0) * DMODEL * DMODEL,
        b1 + (size_t)l * DMODEL,
        (const float*)nullptr, (const float*)nullptr, 0,
        y1_bf, statpart);
    k_bnfin<<<1, DMODEL, 0, stream>>>(statpart,
                                      g1 + (size_t)l * DMODEL, beta1 + (size_t)l * DMODEL,
                                      sArr(l, 0), tArr(l, 0));
    // h = relu(BN1(y1)) @ w2[l] + b2[l]   (stats -> BN2, applied by next consumer)
    k_gemm<<<nbGemm, 256, 0, stream>>>(
        y1_bf,
        wt_hi + (size_t)(l * 2 + 1) * DMODEL * DMODEL,
        wt_lo + (size_t)(l * 2 + 1) * DMODEL * DMODEL,
        b2 + (size_t)l * DMODEL,
        sArr(l, 0), tArr(l, 0), 1,
        h_bf, statpart);
    k_bnfin<<<1, DMODEL, 0, stream>>>(statpart,
                                      ng + (size_t)l * DMODEL, nb + (size_t)l * DMODEL,
                                      sArr(l, 1), tArr(l, 1));
  }

  dim3 poolGrid(NGRAPH, 8);
  k_pool<<<poolGrid, 64, 0, stream>>>(h_bf, gstart, psum);
  k_classifier<<<NGRAPH, DMODEL, 0, stream>>>(psum, gstart, sArr(NLAYERS - 1, 1),
                                              tArr(NLAYERS - 1, 1),
                                              cw1, cb1, cw2, cb2, (float*)d_out);
}

// Round 7
// 713.462 us; speedup vs baseline: 1.6239x; 1.2357x over previous
//
#include <hip/hip_runtime.h>
#include <stdint.h>

#define N_NODES 100000
#define N_EDGES 600000
#define DMODEL  128
#define NLAYERS 4
#define NGRAPH  128
#define NCLASS  10
#define BN_EPS  1e-5f
#define NSLOT   32     // stat partial slots (atomic contention spreading)

typedef __bf16 bf16x8 __attribute__((ext_vector_type(8)));
typedef __bf16 bf16x2 __attribute__((ext_vector_type(2)));
typedef float  f32x4  __attribute__((ext_vector_type(4)));

// ---------------- zero-init scratch we accumulate into ----------------
__global__ void k_zero(int* __restrict__ deg, float* __restrict__ statpart,
                       float* __restrict__ psum) {
  int i = blockIdx.x * 256 + threadIdx.x;
  if (i < N_NODES) deg[i] = 0;
  if (i < NSLOT * 2 * DMODEL) statpart[i] = 0.0f;
  if (i < NGRAPH * DMODEL) psum[i] = 0.0f;
}

// ---------------- embedding gather: h[i,d] = bf16(emb[x[i],d]) ----------------
__global__ void k_embed(const int* __restrict__ x, const float* __restrict__ emb,
                        __bf16* __restrict__ h) {
  int idx = blockIdx.x * 256 + threadIdx.x;        // over N*D/2
  if (idx >= N_NODES * DMODEL / 2) return;
  int i = idx >> 6;
  int p = idx & 63;
  float2 v = *(const float2*)(emb + (size_t)x[i] * DMODEL + p * 2);
  bf16x2 o;
  o[0] = (__bf16)v.x;
  o[1] = (__bf16)v.y;
  *(bf16x2*)(h + (size_t)i * DMODEL + p * 2) = o;
}

// ------- transpose + split-cvt weights: whi+wlo ≈ w^T in 2x bf16 -------
__global__ void k_cvtw(const float* __restrict__ w1, const float* __restrict__ w2,
                       __bf16* __restrict__ wt_hi, __bf16* __restrict__ wt_lo) {
  int idx = blockIdx.x * 256 + threadIdx.x;   // L*2*D*D = 131072
  if (idx >= NLAYERS * 2 * DMODEL * DMODEL) return;
  int mat = idx >> 14;
  int rem = idx & 16383;
  int n = rem >> 7;
  int k = rem & 127;
  int l = mat >> 1;
  int which = mat & 1;
  const float* w = which ? w2 : w1;
  float v = w[(size_t)l * DMODEL * DMODEL + (size_t)k * DMODEL + n];
  __bf16 hi = (__bf16)v;
  wt_hi[idx] = hi;
  wt_lo[idx] = (__bf16)(v - (float)hi);
}

// ---------------- CSR build ----------------
__global__ void k_hist(const int* __restrict__ dst, int* __restrict__ deg) {
  int e = blockIdx.x * 256 + threadIdx.x;
  if (e < N_EDGES) atomicAdd(&deg[dst[e]], 1);
}

__global__ void k_scan1(const int* __restrict__ deg, int* __restrict__ out,
                        int* __restrict__ bsum, int n) {
  __shared__ int lds[256];
  int t = threadIdx.x;
  int idx = blockIdx.x * 256 + t;
  int v = (idx < n) ? deg[idx] : 0;
  int val = v;
  lds[t] = val;
  for (int ofs = 1; ofs < 256; ofs <<= 1) {
    __syncthreads();
    int u = (t >= ofs) ? lds[t - ofs] : 0;
    __syncthreads();
    val += u;
    lds[t] = val;
  }
  if (idx < n) out[idx] = val - v;           // exclusive within chunk
  if (t == 255) bsum[blockIdx.x] = val;      // chunk total
}

__global__ void k_scan2(const int* __restrict__ bsum, int* __restrict__ bsumx, int nb) {
  __shared__ int lds[512];
  int t = threadIdx.x;
  int v = (t < nb) ? bsum[t] : 0;
  int val = v;
  lds[t] = val;
  for (int ofs = 1; ofs < 512; ofs <<= 1) {
    __syncthreads();
    int u = (t >= ofs) ? lds[t - ofs] : 0;
    __syncthreads();
    val += u;
    lds[t] = val;
  }
  if (t < nb) bsumx[t] = val - v;
}

__global__ void k_scan3(int* __restrict__ row_start, int* __restrict__ cursor,
                        const int* __restrict__ bsumx, int n, int total) {
  int idx = blockIdx.x * 256 + threadIdx.x;
  if (idx < n) {
    int v = row_start[idx] + bsumx[blockIdx.x];
    row_start[idx] = v;
    cursor[idx] = v;
  }
  if (idx == 0) row_start[n] = total;
}

// pack each edge as 16B {src, a0, a1, pad} at its CSR slot
__global__ void k_scatter(const int* __restrict__ ei, const float* __restrict__ ea,
                          int* __restrict__ cursor, int4* __restrict__ epack) {
  int e = blockIdx.x * 256 + threadIdx.x;
  if (e >= N_EDGES) return;
  int s = ei[e];
  int d = ei[N_EDGES + e];
  int pos = atomicAdd(&cursor[d], 1);
  int4 pk;
  pk.x = s;
  pk.y = __float_as_int(ea[2 * e]);
  pk.z = __float_as_int(ea[2 * e + 1]);
  pk.w = 0;
  epack[pos] = pk;
}

// ------- message + aggregate: z = act(h_i) + sum_in relu(act(h_src) + edge_lin) -----
// act(h) = relu(s*h + t) when hasT (deferred BN+relu of previous layer), else identity.
// One wave per node: 64 lanes x 2 channels. 4 nodes/block. j-loop unrolled 4x with
// independent gathers (MLP); accumulation order kept sequential (identical rounding).
__global__ void __launch_bounds__(256) k_agg(
    const __bf16* __restrict__ h, const int* __restrict__ row_start,
    const int4* __restrict__ epack,
    const float* __restrict__ ew,   // edge_w + l*2*D, layout [2][D]
    const float* __restrict__ ebp,  // edge_b + l*D
    const float* __restrict__ sIn, const float* __restrict__ tIn, int hasT,
    __bf16* __restrict__ z) {
  int node = blockIdx.x * 4 + (threadIdx.x >> 6);
  if (node >= N_NODES) return;
  int lane = threadIdx.x & 63;
  int d0 = lane * 2;

  float ew0a = ew[d0],          ew0b = ew[d0 + 1];
  float ew1a = ew[DMODEL + d0], ew1b = ew[DMODEL + d0 + 1];
  float eba = ebp[d0],          ebb = ebp[d0 + 1];
  float sa = 1.0f, ta = 0.0f, sb = 1.0f, tb = 0.0f;
  if (hasT) {
    sa = sIn[d0]; ta = tIn[d0];
    sb = sIn[d0 + 1]; tb = tIn[d0 + 1];
  }

  bf16x2 hv = *(const bf16x2*)(h + (size_t)node * DMODEL + d0);
  float r0 = (float)hv[0];
  float r1 = (float)hv[1];
  float acc0 = hasT ? fmaxf(sa * r0 + ta, 0.0f) : r0;   // self term
  float acc1 = hasT ? fmaxf(sb * r1 + tb, 0.0f) : r1;

  int j0 = row_start[node];
  int j1 = row_start[node + 1];
  int j = j0;

#define AGG_ONE(E, V)                                                          \
  {                                                                            \
    float a0 = __int_as_float((E).y);                                          \
    float a1 = __int_as_float((E).z);                                          \
    float f0 = (float)(V)[0];                                                  \
    float f1 = (float)(V)[1];                                                  \
    if (hasT) {                                                                \
      f0 = fmaxf(sa * f0 + ta, 0.0f);                                          \
      f1 = fmaxf(sb * f1 + tb, 0.0f);                                          \
    }                                                                          \
    acc0 += fmaxf(f0 + a0 * ew0a + a1 * ew1a + eba, 0.0f);                     \
    acc1 += fmaxf(f1 + a0 * ew0b + a1 * ew1b + ebb, 0.0f);                     \
  }

  for (; j + 4 <= j1; j += 4) {
    int4 e0 = epack[j];
    int4 e1 = epack[j + 1];
    int4 e2 = epack[j + 2];
    int4 e3 = epack[j + 3];
    bf16x2 v0 = *(const bf16x2*)(h + (size_t)e0.x * DMODEL + d0);
    bf16x2 v1 = *(const bf16x2*)(h + (size_t)e1.x * DMODEL + d0);
    bf16x2 v2 = *(const bf16x2*)(h + (size_t)e2.x * DMODEL + d0);
    bf16x2 v3 = *(const bf16x2*)(h + (size_t)e3.x * DMODEL + d0);
    AGG_ONE(e0, v0)
    AGG_ONE(e1, v1)
    AGG_ONE(e2, v2)
    AGG_ONE(e3, v3)
  }
  for (; j < j1; ++j) {
    int4 e0 = epack[j];
    bf16x2 v0 = *(const bf16x2*)(h + (size_t)e0.x * DMODEL + d0);
    AGG_ONE(e0, v0)
  }
#undef AGG_ONE

  bf16x2 o;
  o[0] = (__bf16)acc0;
  o[1] = (__bf16)acc1;
  *(bf16x2*)(z + (size_t)node * DMODEL + d0) = o;
}

// ---------------- GEMM: Y = act(X) @ W + bias  (bf16 MFMA, split-W, register-B) -----
// act(x) = relu(sIn[k]*x + tIn[k]) when applyIn. X:[N,128] bf16. Whi/Wlo:[n][k] bf16,
// Whi+Wlo ≈ f32 W. Block: 256 thr = 4 waves; wave w owns output cols [32w, 32w+32)
// (2 ct tiles) and holds ALL its B fragments in registers (16 bf16x8 = 64 VGPRs).
// Grid-stride over 32-row chunks (N = 3125*32 exactly -> no bounds checks).
// Column stats accumulated in registers across chunks; one reduce+atomic per block.
// Fragment maps (m89/m92): A[m=lane&15][k=quad*8+j], B[n=lane&15][k=quad*8+j],
// C/D col=lane&15, row=quad*4+reg.
__global__ void __launch_bounds__(256) k_gemm(
    const __bf16* __restrict__ X,
    const __bf16* __restrict__ Whi, const __bf16* __restrict__ Wlo,
    const float* __restrict__ bias,
    const float* __restrict__ sIn, const float* __restrict__ tIn, int applyIn,
    __bf16* __restrict__ Y,
    float* __restrict__ statpart) {
  int tid = threadIdx.x;
  int wave = tid >> 6;
  int lane = tid & 63;
  int n16 = lane & 15;
  int quad = lane >> 4;

  // load this wave's B fragments (2 col-tiles x 4 k-chunks, hi+lo)
  bf16x8 bhi[2][4];
  bf16x8 blo[2][4];
#pragma unroll
  for (int ct = 0; ct < 2; ++ct) {
    int n = (wave * 2 + ct) * 16 + n16;
#pragma unroll
    for (int kk = 0; kk < 4; ++kk) {
      int k0 = kk * 32 + quad * 8;
      bhi[ct][kk] = *(const bf16x8*)(Whi + (size_t)n * DMODEL + k0);
      blo[ct][kk] = *(const bf16x8*)(Wlo + (size_t)n * DMODEL + k0);
    }
  }
  float bc[2];
  bc[0] = bias[(wave * 2 + 0) * 16 + n16];
  bc[1] = bias[(wave * 2 + 1) * 16 + n16];

  float ssum[2] = {0.0f, 0.0f};
  float ssq[2] = {0.0f, 0.0f};

  const int NCHUNK = N_NODES / 32;   // 3125 exact
  for (int c = blockIdx.x; c < NCHUNK; c += gridDim.x) {
    int row0 = c * 32;
    bf16x8 a[2][4];
#pragma unroll
    for (int t = 0; t < 2; ++t) {
      const __bf16* xr = X + (size_t)(row0 + t * 16 + n16) * DMODEL;
#pragma unroll
      for (int kk = 0; kk < 4; ++kk) {
        a[t][kk] = *(const bf16x8*)(xr + kk * 32 + quad * 8);
      }
    }
    if (applyIn) {
#pragma unroll
      for (int kk = 0; kk < 4; ++kk) {
        int k0 = kk * 32 + quad * 8;
        float4 s0 = *(const float4*)(sIn + k0);
        float4 s1 = *(const float4*)(sIn + k0 + 4);
        float4 t0 = *(const float4*)(tIn + k0);
        float4 t1 = *(const float4*)(tIn + k0 + 4);
        float sv[8];
        float tv[8];
        sv[0] = s0.x; sv[1] = s0.y; sv[2] = s0.z; sv[3] = s0.w;
        sv[4] = s1.x; sv[5] = s1.y; sv[6] = s1.z; sv[7] = s1.w;
        tv[0] = t0.x; tv[1] = t0.y; tv[2] = t0.z; tv[3] = t0.w;
        tv[4] = t1.x; tv[5] = t1.y; tv[6] = t1.z; tv[7] = t1.w;
#pragma unroll
        for (int t = 0; t < 2; ++t) {
#pragma unroll
          for (int jj = 0; jj < 8; ++jj) {
            float f = (float)a[t][kk][jj];
            a[t][kk][jj] = (__bf16)fmaxf(sv[jj] * f + tv[jj], 0.0f);
          }
        }
      }
    }

    f32x4 acc[2][2];
#pragma unroll
    for (int t = 0; t < 2; ++t)
#pragma unroll
      for (int ct = 0; ct < 2; ++ct)
#pragma unroll
        for (int r = 0; r < 4; ++r) acc[t][ct][r] = 0.0f;

    // kk -> (hi, lo) order matches previous rounds (identical per-element rounding)
#pragma unroll
    for (int kk = 0; kk < 4; ++kk) {
#pragma unroll
      for (int ct = 0; ct < 2; ++ct) {
#pragma unroll
        for (int t = 0; t < 2; ++t) {
          acc[t][ct] = __builtin_amdgcn_mfma_f32_16x16x32_bf16(a[t][kk], bhi[ct][kk], acc[t][ct], 0, 0, 0);
          acc[t][ct] = __builtin_amdgcn_mfma_f32_16x16x32_bf16(a[t][kk], blo[ct][kk], acc[t][ct], 0, 0, 0);
        }
      }
    }

    // epilogue: bias add, bf16 store, accumulate column stats in registers
#pragma unroll
    for (int t = 0; t < 2; ++t) {
#pragma unroll
      for (int ct = 0; ct < 2; ++ct) {
        int col = (wave * 2 + ct) * 16 + n16;
#pragma unroll
        for (int r = 0; r < 4; ++r) {
          int row = row0 + t * 16 + quad * 4 + r;
          float v = acc[t][ct][r] + bc[ct];
          Y[(size_t)row * DMODEL + col] = (__bf16)v;
          ssum[ct] += v;
          ssq[ct] += v * v;
        }
      }
    }
  }

  // one reduction + atomic per (wave, ct) for the whole block
  int slot = blockIdx.x & (NSLOT - 1);
#pragma unroll
  for (int ct = 0; ct < 2; ++ct) {
    int col = (wave * 2 + ct) * 16 + n16;
    float s = ssum[ct];
    float q = ssq[ct];
    s += __shfl_xor(s, 16);
    q += __shfl_xor(q, 16);
    s += __shfl_xor(s, 32);
    q += __shfl_xor(q, 32);
    if (quad == 0) {
      atomicAdd(&statpart[slot * (2 * DMODEL) + col], s);
      atomicAdd(&statpart[slot * (2 * DMODEL) + DMODEL + col], q);
    }
  }
}

// ------- fold stat partials into BN scale/shift, and re-zero partials -------
__global__ void k_bnfin(float* __restrict__ statpart,
                        const float* __restrict__ gamma, const float* __restrict__ beta,
                        float* __restrict__ sOut, float* __restrict__ tOut) {
  int d = threadIdx.x;   // 128
  float sum = 0.0f;
  float sq = 0.0f;
  for (int p = 0; p < NSLOT; ++p) {
    sum += statpart[p * (2 * DMODEL) + d];
    sq  += statpart[p * (2 * DMODEL) + DMODEL + d];
  }
  float mean = sum * (1.0f / N_NODES);
  float var = sq * (1.0f / N_NODES) - mean * mean;
  float inv = rsqrtf(var + BN_EPS);
  float s = gamma[d] * inv;
  sOut[d] = s;
  tOut[d] = beta[d] - mean * s;
  for (int p = 0; p < NSLOT; ++p) {
    statpart[p * (2 * DMODEL) + d] = 0.0f;
    statpart[p * (2 * DMODEL) + DMODEL + d] = 0.0f;
  }
}

// ------- graph boundaries by binary search over sorted batch -------
__global__ void k_gstart(const int* __restrict__ batch, int* __restrict__ gstart) {
  int g = blockIdx.x * 256 + threadIdx.x;
  if (g > NGRAPH) return;
  int lo = 0;
  int hi = N_NODES;
  while (lo < hi) {
    int mid = (lo + hi) >> 1;
    if (batch[mid] < g) lo = mid + 1; else hi = mid;
  }
  gstart[g] = lo;   // first node with batch >= g; gstart[G] = N
}

// ------- pooling partial sums of raw h (affine deferred to classifier) -------
__global__ void k_pool(const __bf16* __restrict__ h, const int* __restrict__ gstart,
                       float* __restrict__ psum) {
  int g = blockIdx.x;
  int slice = blockIdx.y;   // 0..7
  int lane = threadIdx.x;   // 64
  int d0 = lane * 2;
  int i0 = gstart[g];
  int i1 = gstart[g + 1];
  float a0 = 0.0f;
  float a1 = 0.0f;
  for (int i = i0 + slice; i < i1; i += 8) {
    bf16x2 v = *(const bf16x2*)(h + (size_t)i * DMODEL + d0);
    a0 += (float)v[0];
    a1 += (float)v[1];
  }
  atomicAdd(&psum[g * DMODEL + d0], a0);
  atomicAdd(&psum[g * DMODEL + d0 + 1], a1);
}

// ------- classifier: applies final BN affine + mean, then Linear-ReLU-Linear -------
__global__ void k_classifier(const float* __restrict__ psum, const int* __restrict__ gstart,
                             const float* __restrict__ s2, const float* __restrict__ t2,
                             const float* __restrict__ cw1, const float* __restrict__ cb1,
                             const float* __restrict__ cw2, const float* __restrict__ cb2,
                             float* __restrict__ out) {
  __shared__ float pl[DMODEL];
  __shared__ float hid[DMODEL];
  int g = blockIdx.x;
  int d = threadIdx.x;
  int cnt = gstart[g + 1] - gstart[g];
  pl[d] = (cnt > 0) ? (s2[d] * (psum[g * DMODEL + d] / (float)cnt) + t2[d]) : 0.0f;
  __syncthreads();
  float acc = cb1[d];
  for (int k = 0; k < DMODEL; ++k) acc += pl[k] * cw1[k * DMODEL + d];
  hid[d] = fmaxf(acc, 0.0f);
  __syncthreads();
  if (d < NCLASS) {
    float acc2 = cb2[d];
    for (int k = 0; k < DMODEL; ++k) acc2 += hid[k] * cw2[k * NCLASS + d];
    out[g * NCLASS + d] = acc2;
  }
}

// ---------------- launcher ----------------
extern "C" void kernel_launch(void* const* d_in, const int* in_sizes, int n_in,
                              void* d_out, int out_size, void* d_ws, size_t ws_size,
                              hipStream_t stream) {
  const int*   x      = (const int*)d_in[0];
  const int*   ei     = (const int*)d_in[1];
  const float* ea     = (const float*)d_in[2];
  const int*   batch  = (const int*)d_in[3];
  const float* emb    = (const float*)d_in[4];
  const float* edge_w = (const float*)d_in[5];
  const float* edge_b = (const float*)d_in[6];
  const float* w1     = (const float*)d_in[7];
  const float* b1     = (const float*)d_in[8];
  const float* g1     = (const float*)d_in[9];
  const float* beta1  = (const float*)d_in[10];
  const float* w2     = (const float*)d_in[11];
  const float* b2     = (const float*)d_in[12];
  const float* ng     = (const float*)d_in[13];
  const float* nb     = (const float*)d_in[14];
  const float* cw1    = (const float*)d_in[15];
  const float* cb1    = (const float*)d_in[16];
  const float* cw2    = (const float*)d_in[17];
  const float* cb2    = (const float*)d_in[18];

  char* ws = (char*)d_ws;
  size_t off = 0;
  auto alloc = [&](size_t bytes) -> void* {
    void* p = ws + off;
    off += (bytes + 255) & ~(size_t)255;
    return p;
  };

  __bf16* h_bf      = (__bf16*)alloc((size_t)N_NODES * DMODEL * sizeof(__bf16));
  __bf16* z_bf      = (__bf16*)alloc((size_t)N_NODES * DMODEL * sizeof(__bf16));
  __bf16* y1_bf     = (__bf16*)alloc((size_t)N_NODES * DMODEL * sizeof(__bf16));
  int*    row_start = (int*)alloc((N_NODES + 1) * sizeof(int));
  int*    cursor    = (int*)alloc(N_NODES * sizeof(int));
  int*    deg       = (int*)alloc(N_NODES * sizeof(int));
  int4*   epack     = (int4*)alloc((size_t)N_EDGES * sizeof(int4));
  __bf16* wt_hi     = (__bf16*)alloc((size_t)NLAYERS * 2 * DMODEL * DMODEL * sizeof(__bf16));
  __bf16* wt_lo     = (__bf16*)alloc((size_t)NLAYERS * 2 * DMODEL * DMODEL * sizeof(__bf16));
  float*  statpart  = (float*)alloc((size_t)NSLOT * 2 * DMODEL * sizeof(float));
  float*  st        = (float*)alloc((size_t)NLAYERS * 2 * 2 * DMODEL * sizeof(float));
  int*    gstart    = (int*)alloc((NGRAPH + 1) * sizeof(int));
  float*  psum      = (float*)alloc((size_t)NGRAPH * DMODEL * sizeof(float));
  int*    bsum      = (int*)alloc(512 * sizeof(int));
  int*    bsumx     = (int*)alloc(512 * sizeof(int));

  auto sArr = [&](int l, int which) { return st + ((l * 2 + which) * 2 + 0) * DMODEL; };
  auto tArr = [&](int l, int which) { return st + ((l * 2 + which) * 2 + 1) * DMODEL; };

  const int nbScan = (N_NODES + 255) / 256;              // 391
  const int nbEdge = (N_EDGES + 255) / 256;              // 2344
  const int nbEmb  = (N_NODES * DMODEL / 2 + 255) / 256; // 25000
  const int nbGemm = 782;                                // grid-stride over 3125 chunks
  const int nbAgg  = (N_NODES + 3) / 4;                  // 25000

  k_zero<<<nbScan, 256, 0, stream>>>(deg, statpart, psum);
  k_embed<<<nbEmb, 256, 0, stream>>>(x, emb, h_bf);
  k_cvtw<<<(NLAYERS * 2 * DMODEL * DMODEL) / 256, 256, 0, stream>>>(w1, w2, wt_hi, wt_lo);
  k_hist<<<nbEdge, 256, 0, stream>>>(ei + N_EDGES, deg);
  k_scan1<<<nbScan, 256, 0, stream>>>(deg, row_start, bsum, N_NODES);
  k_scan2<<<1, 512, 0, stream>>>(bsum, bsumx, nbScan);
  k_scan3<<<nbScan, 256, 0, stream>>>(row_start, cursor, bsumx, N_NODES, N_EDGES);
  k_scatter<<<nbEdge, 256, 0, stream>>>(ei, ea, cursor, epack);
  k_gstart<<<1, 256, 0, stream>>>(batch, gstart);

  for (int l = 0; l < NLAYERS; ++l) {
    const float* sI = (l > 0) ? sArr(l - 1, 1) : (const float*)nullptr;
    const float* tI = (l > 0) ? tArr(l - 1, 1) : (const float*)nullptr;
    k_agg<<<nbAgg, 256, 0, stream>>>(h_bf, row_start, epack,
                                     edge_w + (size_t)l * 2 * DMODEL,
                                     edge_b + (size_t)l * DMODEL,
                                     sI, tI, (l > 0) ? 1 : 0, z_bf);
    // y1 = z @ w1[l] + b1[l]   (stats -> BN1)
    k_gemm<<<nbGemm, 256, 0, stream>>>(
        z_bf,
        wt_hi + (size_t)(l * 2 + 0) * DMODEL * DMODEL,
        wt_lo + (size_t)(l * 2 + 0) * DMODEL * DMODEL,
        b1 + (size_t)l * DMODEL,
        (const float*)nullptr, (const float*)nullptr, 0,
        y1_bf, statpart);
    k_bnfin<<<1, DMODEL, 0, stream>>>(statpart,
                                      g1 + (size_t)l * DMODEL, beta1 + (size_t)l * DMODEL,
                                      sArr(l, 0), tArr(l, 0));
    // h = relu(BN1(y1)) @ w2[l] + b2[l]   (stats -> BN2, applied by next consumer)
    k_gemm<<<nbGemm, 256, 0, stream>>>(
        y1_bf,
        wt_hi + (size_t)(l * 2 + 1) * DMODEL * DMODEL,
        wt_lo + (size_t)(l * 2 + 1) * DMODEL * DMODEL,
        b2 + (size_t)l * DMODEL,
        sArr(l, 0), tArr(l, 0), 1,
        h_bf, statpart);
    k_bnfin<<<1, DMODEL, 0, stream>>>(statpart,
                                      ng + (size_t)l * DMODEL, nb + (size_t)l * DMODEL,
                                      sArr(l, 1), tArr(l, 1));
  }

  dim3 poolGrid(NGRAPH, 8);
  k_pool<<<poolGrid, 64, 0, stream>>>(h_bf, gstart, psum);
  k_classifier<<<NGRAPH, DMODEL, 0, stream>>>(psum, gstart, sArr(NLAYERS - 1, 1),
                                              tArr(NLAYERS - 1, 1),
                                              cw1, cb1, cw2, cb2, (float*)d_out);
}